// Round 6
// baseline (1472.948 us; speedup 1.0000x reference)
//
#include <hip/hip_runtime.h>
#include <hip/hip_fp8.h>

#define F_DIM 512
#define H_DIM 2048
#define V_DIM 32000
#define B_DIM 64
#define S_DIM 256
#define ROWS (S_DIM*B_DIM)          // 16384
#define NT_LOG 250                  // 32000/128
#define SCALE 0.04419417382415922f  // 1/sqrt(512)
#define LSE_OFF 40.0f               // fixed softmax offset; |logit*SCALE| ~ O(8)

typedef __attribute__((ext_vector_type(8))) short  short8;
typedef __attribute__((ext_vector_type(4))) float  floatx4;
typedef __attribute__((ext_vector_type(4))) int    intx4;
typedef __attribute__((ext_vector_type(8))) int    i32x8;
typedef __attribute__((ext_vector_type(4))) unsigned int uix4;

static __device__ inline unsigned short f2bf(float x){
  unsigned int u = __float_as_uint(x);
  u += 0x7fffu + ((u >> 16) & 1u);           // RNE
  return (unsigned short)(u >> 16);
}
static __device__ inline float bf2f(unsigned short u){
  return __uint_as_float(((unsigned int)u) << 16);
}
static __device__ inline unsigned char f2fp8(float x){
  __hip_fp8_e4m3 q(x);
  return q.__x;
}
// fp8-buffer bank swizzle: within each 64-B segment of a row, granule g (8 B)
// is stored at chunk=(g>>1)^((row>>1)&3), lob=(g&1)^((row>>3)&1). With this,
// a 16-lane ds_read_b64 phase in gemm_f8_logits covers all 32 banks exactly
// once (r9 lesson: staging's 16-B atomicity forbids fixing lob at load time).
static __device__ inline int sw8(int row, int col){
  int g = (col >> 3) & 7;
  int chunk = ((g >> 1) ^ ((row >> 1) & 3));
  int lob = (g & 1) ^ ((row >> 3) & 1);
  return (col & ~63) | (chunk << 4) | (lob << 3) | (col & 7);
}
// ZV permutation within each 64-word group: col c -> (c&~63)|((c&15)<<2)|((c>>4)&3)
// so the recurrence thread (rl) reads its 4 words (tl=0..3) contiguously (dwordx4).
static __device__ inline int zvperm(int c){
  return (c & ~63) | ((c & 15) << 2) | ((c >> 4) & 3);
}
static __device__ inline float wsum(float v){
  #pragma unroll
  for(int m = 32; m > 0; m >>= 1) v += __shfl_xor(v, m);
  return v;
}
static __device__ inline void load_lds16(const void* g, void* l){
  __builtin_amdgcn_global_load_lds((const __attribute__((address_space(1))) void*)g,
                                   (__attribute__((address_space(3))) void*)l, 16, 0, 0);
}
static __device__ inline i32x8 asm8(long a, long b, long c, long d){
  i32x8 r;
  r[0]=(int)a; r[1]=(int)(a>>32); r[2]=(int)b; r[3]=(int)(b>>32);
  r[4]=(int)c; r[5]=(int)(c>>32); r[6]=(int)d; r[7]=(int)(d>>32);
  return r;
}

// ---------------- casts ----------------
__global__ __launch_bounds__(256) void cast_w(const float* __restrict__ src,
                                              unsigned short* __restrict__ dst, int n){
  int i = blockIdx.x*256 + threadIdx.x;
  int stride = gridDim.x*256;
  for(; i < n; i += stride) dst[i] = f2bf(src[i]);
}
// emb -> bf16 (for tlogit) + fp8 bank-swizzled (for logits GEMM), PAD row zeroed
__global__ __launch_bounds__(256) void cast_emb(const float* __restrict__ src,
    unsigned short* __restrict__ dst, unsigned char* __restrict__ d8){
  int i = blockIdx.x*256 + threadIdx.x;
  int stride = gridDim.x*256;
  for(; i < V_DIM*F_DIM; i += stride){
    float v = (i < F_DIM) ? 0.f : src[i];
    dst[i] = f2bf(v);
    int row = i >> 9, col = i & 511;
    d8[(long)row*512 + sw8(row, col)] = f2fp8(v);
  }
}

// ---------------- prep: see_top^T bf16 (for Z gemm) + see_bot^T fp8 ----------
__global__ __launch_bounds__(256) void prep_see(const float* __restrict__ see,
    unsigned short* __restrict__ TT, unsigned char* __restrict__ B8){
  int n = blockIdx.x;
  for(int k = threadIdx.x; k < 512; k += 256){
    TT[n*512 + k] = f2bf(see[(long)k*512 + n]);
    B8[n*512 + k] = f2fp8(see[(long)(512+k)*512 + n]);
  }
}

// ---------------- gather embedding rows per (t,b), bf16; row = t*64+b -------
__global__ __launch_bounds__(256) void gather_vecs(const float* __restrict__ emb,
    const int* __restrict__ inp, unsigned short* __restrict__ V){
  long row = (long)blockIdx.x*4 + (threadIdx.x >> 6);
  int l = threadIdx.x & 63;
  int t = (int)(row >> 6), b = (int)(row & 63);
  int idx = inp[b*S_DIM + t];
  short8 o;
  if (idx == 0){
    #pragma unroll
    for(int i=0;i<8;i++) o[i] = 0;
  } else {
    const float* e = emb + (long)idx*F_DIM + l*8;
    float4 a = *(const float4*)e;
    float4 bq = *(const float4*)(e + 4);
    o[0]=(short)f2bf(a.x); o[1]=(short)f2bf(a.y); o[2]=(short)f2bf(a.z); o[3]=(short)f2bf(a.w);
    o[4]=(short)f2bf(bq.x);o[5]=(short)f2bf(bq.y);o[6]=(short)f2bf(bq.z);o[7]=(short)f2bf(bq.w);
  }
  *(short8*)(V + row*F_DIM + l*8) = o;
}

// ---------------- batch-parallel recurrence, fp8-resident weights ----------
// r10: raw s_barrier (lgkmcnt-only) — HIP __syncthreads drains vmcnt(0).
// r11: HW packed cvts + v_rcp sigmoid (epilogue was VALU-issue-bound).
// r13: MX-scaled fp8 K=128 MFMA (unit scales) + per-tl MFMA/epilogue
// interleave + permuted ZV layout (dwordx4 loads).
__global__ __launch_bounds__(512, 1) void recurrence_batch(
    const unsigned int* __restrict__ ZV,       // [16384][512] permuted groups (zvperm)
    const unsigned char* __restrict__ W8,      // seeBotT fp8 [n=512][k=512]
    unsigned short* __restrict__ CONTB)        // [256][64][512] bf16 state history
{
  __shared__ unsigned char stt[2][16][560];    // 560 = b128-aligned pad, uniform banks

  const int tid = threadIdx.x;
  const int w  = tid >> 6;       // wave 0..7 -> cols w*64..
  const int l  = tid & 63;
  const int rl = l & 15, rq = l >> 4;
  const int wg = blockIdx.x;     // batch rows wg*16..
  const int colb = w*64;

  // persistent fp8 B fragments for MX K=128: [k-tile][n-tile], 8 VGPRs each
  // col = colb+tl*16+rl, k = kt*128 + rq*32 .. +31
  i32x8 Bfr[4][4];
  #pragma unroll
  for(int kt=0;kt<4;kt++)
    #pragma unroll
    for(int tl=0;tl<4;tl++)
      Bfr[kt][tl] = *(const i32x8*)(W8 + (long)(colb + tl*16 + rl)*512 + kt*128 + rq*32);

  float s_old[16];
  #pragma unroll
  for(int i=0;i<16;i++) s_old[i] = 0.f;

  // per-thread ZV base: rows wg*16+rq*4+r, permuted words colb+rl*4 .. +3
  const unsigned int* zbase = ZV + (long)(wg*16 + rq*4)*512 + colb + rl*4;
  unsigned short* cbase = CONTB + ((long)wg*16 + rq*4)*512 + colb + rl;

  uix4 zv[4];
  #pragma unroll
  for(int r=0;r<4;r++) zv[r] = *(const uix4*)(zbase + (long)r*512);

  for(int t = 0; t < S_DIM; t++){
    // cross-wave visibility of prev-step LDS state: LDS ops only.
    asm volatile("s_waitcnt lgkmcnt(0)" ::: "memory");
    __builtin_amdgcn_s_barrier();
    asm volatile("" ::: "memory");   // no LDS-read hoisting above the barrier

    floatx4 acc[4];
    #pragma unroll
    for(int tl=0;tl<4;tl++) acc[tl] = (floatx4)0.f;

    i32x8 afr[4];
    if (t > 0){
      const unsigned char* sb = &stt[(t-1)&1][0][0] + rl*560 + rq*32;
      #pragma unroll
      for(int kt=0;kt<4;kt++){
        intx4 a0 = *(const intx4*)(sb + kt*128);
        intx4 a1 = *(const intx4*)(sb + kt*128 + 16);
        afr[kt] = __builtin_shufflevector(a0, a1, 0,1,2,3,4,5,6,7);
      }
    }

    unsigned short* cw = cbase + (long)t*64*512;
    unsigned char* swb = &stt[t&1][0][0] + rq*4*560 + colb + rl;

    #pragma unroll
    for(int tl=0;tl<4;tl++){
      if (t > 0){
        #pragma unroll
        for(int kt=0;kt<4;kt++)
          acc[tl] = __builtin_amdgcn_mfma_scale_f32_16x16x128_f8f6f4(
                        afr[kt], Bfr[kt][tl], acc[tl],
                        0, 0,                    // cbsz/blgp: fp8 e4m3 both
                        0, 0x7f7f7f7f,           // scale A opsel, value (2^0)
                        0, 0x7f7f7f7f);          // scale B opsel, value (2^0)
      }
      // epilogue for this tl overlaps the other tl chains' MFMA issue
      float sv[4];
      #pragma unroll
      for(int r=0;r<4;r++){
        unsigned int p = zv[r][tl];
        float z = __uint_as_float(p << 16) + acc[tl][r];       // bf2f(lo)
        float v = __uint_as_float(p & 0xffff0000u);            // bf2f(hi)
        float e = __expf(-z);
        float g = __builtin_amdgcn_rcpf(1.f + e);              // sigmoid
        float s = fmaf(s_old[tl*4+r] - v, g, v);
        s_old[tl*4+r] = s;
        sv[r] = s;
      }
      #pragma unroll
      for(int pr=0; pr<2; pr++){
        unsigned int bfp, f8p;
        asm("v_cvt_pk_bf16_f32 %0, %1, %2" : "=v"(bfp) : "v"(sv[pr*2]), "v"(sv[pr*2+1]));
        asm("v_cvt_pk_fp8_f32 %0, %1, %2"  : "=v"(f8p) : "v"(sv[pr*2]), "v"(sv[pr*2+1]));
        cw[(long)(pr*2)*512   + tl*16] = (unsigned short)(bfp & 0xffffu);
        cw[(long)(pr*2+1)*512 + tl*16] = (unsigned short)(bfp >> 16);
        swb[(pr*2)*560   + tl*16] = (unsigned char)(f8p & 0xffu);
        swb[(pr*2+1)*560 + tl*16] = (unsigned char)((f8p >> 8) & 0xffu);
      }
    }

    // load next step's ZV (WAR-ordered after last zv use; latency hides under
    // next step's barrier + MFMA chains; ZV is L3-resident)
    if (t+1 < S_DIM){
      const unsigned int* zp = zbase + (long)(t+1)*64*512;
      #pragma unroll
      for(int r=0;r<4;r++) zv[r] = *(const uix4*)(zp + (long)r*512);
    }
  }
}

// ---------------- layernorm (bf16 in) + bf16 cast; 1 row per wave ----------------
__global__ __launch_bounds__(256) void ln_kernel(const unsigned short* __restrict__ contb,
    const float* __restrict__ lg, const float* __restrict__ lb,
    unsigned short* __restrict__ xln)
{
  const int wid = threadIdx.x >> 6, l = threadIdx.x & 63;
  const long row = (long)blockIdx.x*4 + wid;
  short8 xv = *(const short8*)(contb + row*F_DIM + l*8);
  float v[8];
  #pragma unroll
  for(int i=0;i<8;i++) v[i] = bf2f((unsigned short)xv[i]);
  float s = 0.f;
  #pragma unroll
  for(int i=0;i<8;i++) s += v[i];
  s = wsum(s);
  float mu = s * (1.f/512.f);
  float q = 0.f;
  #pragma unroll
  for(int i=0;i<8;i++){ float d = v[i]-mu; q += d*d; }
  q = wsum(q);
  float rs = rsqrtf(q*(1.f/512.f) + 1e-5f);
  short8 o;
  #pragma unroll
  for(int i=0;i<8;i++)
    o[i] = (short)f2bf((v[i]-mu)*rs*lg[l*8+i] + lb[l*8+i]);
  *(short8*)(xln + row*F_DIM + l*8) = o;
}

// ---------------- bf16 MFMA GEMM: C[M,N] = A[M,K] * B[N,K]^T ----------------
// XOR-swizzled LDS (r6: conflicts 1.97e8 -> 0).
// MODE 0: +bias, relu, store bf16.
// MODE 4: +bias, store bf16 AND bank-swizzled fp8 (logits-GEMM input; N must be 512).
// MODE 5: +bias, store packed ZV word (vzperm'd col): (Vsrc<<16)|bf16(v).
template<int MODE>
__global__ __launch_bounds__(256) void gemm_bt(
    const unsigned short* __restrict__ A,
    const unsigned short* __restrict__ Bm,
    const float* __restrict__ bias,
    unsigned short* __restrict__ C,
    unsigned char* __restrict__ C8,
    const unsigned short* __restrict__ Vsrc,
    unsigned int* __restrict__ ZVout,
    int M, int N, int K, int tiles_m, int tiles_n)
{
  __shared__ short As[128*64];
  __shared__ short Bs[128*64];

  const int bid = blockIdx.x;
  const int mt = bid % tiles_m;
  const int nt = bid / tiles_m;
  const long m0 = (long)mt * 128;
  const long n0 = (long)nt * 128;
  const int tid = threadIdx.x;
  const int l = tid & 63;
  const int wid = tid >> 6;
  const int wr = wid >> 1, wc = wid & 1;
  const int rl = l & 15, rq = l >> 4;

  const short* Ag = (const short*)A + m0 * K;
  const short* Bg = (const short*)Bm + n0 * K;
  const int grow = tid >> 3;   // 0..31
  const int kp = tid & 7;      // 0..7
  const int ksw = (kp ^ (grow & 7)) * 8;   // swizzled global chunk offset (shorts)

  floatx4 acc[4][4];
  #pragma unroll
  for(int i=0;i<4;i++)
    #pragma unroll
    for(int j=0;j<4;j++) acc[i][j] = (floatx4)0.f;

  for(int k0 = 0; k0 < K; k0 += 64){
    __syncthreads();
    #pragma unroll
    for(int ro = 0; ro < 128; ro += 32){
      load_lds16(Ag + (long)(ro + grow)*K + k0 + ksw, (void*)(As + (ro+grow)*64 + kp*8));
      load_lds16(Bg + (long)(ro + grow)*K + k0 + ksw, (void*)(Bs + (ro+grow)*64 + kp*8));
    }
    __syncthreads();
    #pragma unroll
    for(int kb = 0; kb < 64; kb += 32){
      const int cb = kb >> 3;              // base chunk: 0 or 4
      const int cl = ((cb + rq) ^ (rl & 7)) * 8;   // swizzled LDS chunk (shorts)
      short8 af[4], bfr[4];
      #pragma unroll
      for(int i=0;i<4;i++) af[i]  = *(const short8*)(As + (wr*64 + i*16 + rl)*64 + cl);
      #pragma unroll
      for(int j=0;j<4;j++) bfr[j] = *(const short8*)(Bs + (wc*64 + j*16 + rl)*64 + cl);
      #pragma unroll
      for(int i=0;i<4;i++)
        #pragma unroll
        for(int j=0;j<4;j++)
          acc[i][j] = __builtin_amdgcn_mfma_f32_16x16x32_bf16(af[i], bfr[j], acc[i][j], 0, 0, 0);
    }
  }

  const long mb = m0 + wr*64;
  const long nb = n0 + wc*64;
  #pragma unroll
  for(int j=0;j<4;j++){
    float bj = bias[nb + j*16 + rl];
    #pragma unroll
    for(int i=0;i<4;i++){
      #pragma unroll
      for(int r=0;r<4;r++){
        float v = acc[i][j][r] + bj;
        if (MODE == 0) v = fmaxf(v, 0.f);
        int rowI = (int)(mb + i*16 + rq*4 + r);
        int colI = (int)(nb + j*16 + rl);
        long idx = (long)rowI*N + colI;
        if (MODE == 5){
          ZVout[(long)rowI*N + zvperm(colI)] =
              ((unsigned)Vsrc[idx] << 16) | (unsigned)f2bf(v);
        } else {
          C[idx] = f2bf(v);
          if (MODE == 4) C8[(long)rowI*512 + sw8(rowI, colI)] = f2fp8(v);
        }
      }
    }
  }
}

// ---------------- fp8 logits GEMM + fixed-offset softmax partials ----------
// Inputs PRE-BANK-SWIZZLED (sw8); staging identity; zero LDS conflicts.
// r12 (T3+T4+T5): counted-vmcnt double-buffer pipeline (K-step 64, 33.8 KB
// LDS -> 4 blocks/CU of cross-block phase overlap).
// r14: MX K=128 MFMA but 66.5 KB LDS -> 2 blocks/CU: REGRESSED (MfmaUtil
// 18.5%) — the phase gaps lost their TLP filler.
// r15: MX rate at r12's LDS footprint. The K=128 fragment splits across two
// 64-wide tiles: lane rq's 32 B lies wholly in tile parity (rq>>1), local
// granule g=(rq&1)*4+j (same sw8 offsets as r14 — conflict-free, bit-exact).
// Per 64-tile: half-wave (seg==t&1) reads its fragment regs; odd t issues
// the 16 MX MFMAs for the completed pair. vmcnt(4) steady state, as r12.
__global__ __launch_bounds__(256) void gemm_f8_logits(
    const unsigned char* __restrict__ A8,
    const unsigned char* __restrict__ B8,
    float* __restrict__ part,
    int M, int N, int K, int tiles_m, int tiles_n)
{
  __shared__ unsigned char As8[2][128*64];
  __shared__ unsigned char Bs8[2][128*64];
  __shared__ float sm2[2][64][2];

  const int bid = blockIdx.x;
  const int mt = bid % tiles_m;
  const int nt = bid / tiles_m;
  const long m0 = (long)mt * 128;
  const long n0 = (long)nt * 128;
  const int tid = threadIdx.x;
  const int l = tid & 63;
  const int wid = tid >> 6;
  const int wr = wid >> 1, wc = wid & 1;
  const int rl = l & 15, rq = l >> 4;

  const unsigned char* Ag = A8 + m0 * K;
  const unsigned char* Bg = B8 + n0 * K;
  const int grow = tid >> 2;               // 0..63
  const int kp = tid & 3;                  // 0..3

  floatx4 acc[4][4];
  #pragma unroll
  for(int i=0;i<4;i++)
    #pragma unroll
    for(int j=0;j<4;j++) acc[i][j] = (floatx4)0.f;

  // per-lane read swizzle pieces (row bits come from rl only; wave/tile bases
  // are multiples of 16 so their bits 1..3 contributions vanish)
  const int rsw = (rl >> 1) & 3;
  const int rhi = (rl >> 3) & 1;
  const int seg = rq >> 1;                 // which 64-tile parity serves this lane
  // local granule offsets for the lane's 32 B within its tile: g=(rq&1)*4+j
  int cl[4];
  #pragma unroll
  for(int j=0;j<4;j++){
    int g = ((rq & 1) << 2) + j;
    cl[j] = ((((g >> 1) ^ rsw)) << 4) | (((g & 1) ^ rhi) << 3);
  }

  const int nkt = K >> 6;                  // 8 K-tiles of 64

  // stage K-tile kk into buffer bb (4 global_load_lds / thread)
  #define STAGE_F8(bb, kk) do {                                               \
    const long kof = (long)(kk)*64 + kp*16;                                   \
    load_lds16(Ag + (long)grow*K       + kof, (void*)(&As8[bb][grow*64       + kp*16])); \
    load_lds16(Ag + (long)(64+grow)*K  + kof, (void*)(&As8[bb][(64+grow)*64  + kp*16])); \
    load_lds16(Bg + (long)grow*K       + kof, (void*)(&Bs8[bb][grow*64       + kp*16])); \
    load_lds16(Bg + (long)(64+grow)*K  + kof, (void*)(&Bs8[bb][(64+grow)*64  + kp*16])); \
  } while(0)

  STAGE_F8(0, 0);
  STAGE_F8(1, 1);

  i32x8 af[4], bfv[4];     // live across even->odd tile (per-lane half of the pair)

  for(int t = 0; t < nkt; t++){
    // tile t staged (t+1's 4 loads may remain in flight)
    if (t < nkt-1) asm volatile("s_waitcnt vmcnt(4)" ::: "memory");
    else           asm volatile("s_waitcnt vmcnt(0)" ::: "memory");
    __builtin_amdgcn_s_barrier();
    __builtin_amdgcn_sched_barrier(0);

    if (seg == (t & 1)){
      const unsigned char* Abuf = &As8[t & 1][0];
      const unsigned char* Bbuf = &Bs8[t & 1][0];
      #pragma unroll
      for(int i=0;i<4;i++){
        const unsigned char* rb = Abuf + (wr*64 + i*16 + rl)*64;
        af[i] = asm8(*(const long*)(rb + cl[0]), *(const long*)(rb + cl[1]),
                     *(const long*)(rb + cl[2]), *(const long*)(rb + cl[3]));
      }
      #pragma unroll
      for(int j=0;j<4;j++){
        const unsigned char* rb = Bbuf + (wc*64 + j*16 + rl)*64;
        bfv[j] = asm8(*(const long*)(rb + cl[0]), *(const long*)(rb + cl[1]),
                      *(const long*)(rb + cl[2]), *(const long*)(rb + cl[3]));
      }
    }
    asm volatile("s_waitcnt lgkmcnt(0)" ::: "memory");
    __builtin_amdgcn_sched_barrier(0);
    __builtin_amdgcn_s_barrier();                    // all reads done: buffer free
    __builtin_amdgcn_sched_barrier(0);

    if (t+2 < nkt) STAGE_F8(t & 1, t+2);             // async refill, 2 iters of flight

    if (t & 1){                                      // K-128 pair complete
      __builtin_amdgcn_s_setprio(1);
      #pragma unroll
      for(int i=0;i<4;i++)
        #pragma unroll
        for(int j=0;j<4;j++)
          acc[i][j] = __builtin_amdgcn_mfma_scale_f32_16x16x128_f8f6f4(
                          af[i], bfv[j], acc[i][j],
                          0, 0, 0, 0x7f7f7f7f, 0, 0x7f7f7f7f);
      __builtin_amdgcn_s_setprio(0);
    }
  }
  #undef STAGE_F8

  // fixed-offset sum-exp partials per 128-col tile
  #pragma unroll
  for(int i=0;i<4;i++){
    #pragma unroll
    for(int r=0;r<4;r++){
      float sv = 0.f;
      #pragma unroll
      for(int j=0;j<4;j++) sv += __expf(acc[i][j][r]*SCALE - LSE_OFF);
      #pragma unroll
      for(int d=1; d<16; d<<=1) sv += __shfl_xor(sv, d);
      if (rl == 0) sm2[wr][i*16 + rq*4 + r][wc] = sv;
    }
  }
  __syncthreads();
  if (tid < 128){
    int wr2 = tid >> 6, rowl = tid & 63;
    part[(m0 + wr2*64 + rowl)*tiles_n + nt] = sm2[wr2][rowl][0] + sm2[wr2][rowl][1];
  }
}

// ---------------- target logit (bf16 inputs) ----------------
__global__ __launch_bounds__(256) void tlogit_kernel(const unsigned short* __restrict__ outb,
    const unsigned short* __restrict__ embb, const int* __restrict__ tgt,
    float* __restrict__ TL)
{
  long gw = (long)blockIdx.x*4 + (threadIdx.x >> 6);
  int l = threadIdx.x & 63;
  int t = (int)(gw >> 6), b = (int)(gw & 63);
  int tg = tgt[b*S_DIM + t];
  const unsigned short* o = outb + gw*F_DIM;
  const unsigned short* e = embb + (long)tg*F_DIM;
  short8 ov = *(const short8*)(o + l*8);
  short8 ev = *(const short8*)(e + l*8);
  float s = 0.f;
  #pragma unroll
  for(int i=0;i<8;i++) s += bf2f((unsigned short)ov[i]) * bf2f((unsigned short)ev[i]);
  s = wsum(s);
  if (l == 0) TL[gw] = s * SCALE;
}

// ---------------- sum partials -> nll ----------------
__global__ __launch_bounds__(256) void lse_kernel(const float* __restrict__ part,
    const float* __restrict__ TL, float* __restrict__ nll)
{
  long row = (long)blockIdx.x*4 + (threadIdx.x >> 6);
  int l = threadIdx.x & 63;
  float S = 0.f;
  for(int c = l; c < NT_LOG; c += 64)
    S += part[row*NT_LOG + c];
  S = wsum(S);
  if (l == 0) nll[row] = (LSE_OFF + logf(S)) - TL[row];
}

// ---------------- final loss ----------------
__global__ __launch_bounds__(256) void loss_kernel(const float* __restrict__ nll,
    const int* __restrict__ tgt, float* __restrict__ out)
{
  int t = threadIdx.x;
  float s = 0.f; int cnt = 0;
  for(int b = 0; b < B_DIM; b++){
    int v = tgt[b*S_DIM + t];
    if (v != 0){ s += nll[(long)t*B_DIM + b]; cnt++; }
  }
  float li = s / fmaxf((float)cnt, 1.f);
  li = wsum(li);
  __shared__ float red[4];
  if ((t & 63) == 0) red[t >> 6] = li;
  __syncthreads();
  if (t == 0) out[0] = (red[0]+red[1]+red[2]+red[3]) * (1.f/256.f);
}

extern "C" void kernel_launch(void* const* d_in, const int* in_sizes, int n_in,
                              void* d_out, int out_size, void* d_ws, size_t ws_size,
                              hipStream_t stream)
{
  const int*   inp   = (const int*)d_in[0];
  const int*   tgt   = (const int*)d_in[1];
  const float* see   = (const float*)d_in[2];
  const float* bias  = (const float*)d_in[3];
  const float* W_in  = (const float*)d_in[4];
  const float* b_in  = (const float*)d_in[5];
  const float* W_out = (const float*)d_in[6];
  const float* b_out = (const float*)d_in[7];
  const float* ln_g  = (const float*)d_in[8];
  const float* ln_b  = (const float*)d_in[9];
  const float* emb   = (const float*)d_in[10];

  // Workspace plan — peak ~205 MB. Aliases safe by stream order:
  //   XLN  aliases ZV     (ZV dead after recurrence; XLN born at ln)
  //   OUT8 aliases VECSb  (VECSb dead after Z-gemm; OUT8 born at FFN2)
  //   PART aliases Hb     (Hb dead after FFN2; PART born at logits gemm)
  char* p = (char*)d_ws;
  unsigned short* CONTB= (unsigned short*)p; p += (size_t)ROWS*F_DIM*2;   // 16.8 MB
  unsigned short* Hb   = (unsigned short*)p; p += (size_t)ROWS*H_DIM*2;   // 67.1 MB
  unsigned short* OUTb = (unsigned short*)p; p += (size_t)ROWS*F_DIM*2;   // 16.8 MB
  unsigned short* EMBb = (unsigned short*)p; p += (size_t)V_DIM*F_DIM*2;  // 32.8 MB
  unsigned char* EMB8  = (unsigned char*)p;  p += (size_t)V_DIM*F_DIM;    // 16.4 MB
  unsigned short* WINb = (unsigned short*)p; p += (size_t)H_DIM*F_DIM*2;  //  2.1 MB
  unsigned short* WOUTb= (unsigned short*)p; p += (size_t)F_DIM*H_DIM*2;  //  2.1 MB
  float* TL            = (float*)p;          p += (size_t)ROWS*4;
  float* NLL           = (float*)p;          p += (size_t)ROWS*4;
  unsigned short* VECSb= (unsigned short*)p; p += (size_t)ROWS*F_DIM*2;   // 16.8 MB
  unsigned int* ZV     = (unsigned int*)p;   p += (size_t)ROWS*F_DIM*4;   // 33.6 MB
  unsigned short* SEETT= (unsigned short*)p; p += (size_t)F_DIM*F_DIM*2;  //  0.5 MB
  unsigned char* SEEB8 = (unsigned char*)p;  p += (size_t)F_DIM*F_DIM;    //  0.26 MB
  // aliases
  unsigned short* XLN  = (unsigned short*)ZV;      // 16.8 of 33.6 MB
  unsigned char* OUT8  = (unsigned char*)VECSb;    //  8.4 of 16.8 MB
  float* PART          = (float*)Hb;               // 16.4 of 67.1 MB

  // independent prep
  cast_emb<<<4096, 256, 0, stream>>>(emb, EMBb, EMB8);
  cast_w<<<2048, 256, 0, stream>>>(W_in,  WINb,  H_DIM*F_DIM);
  cast_w<<<2048, 256, 0, stream>>>(W_out, WOUTb, F_DIM*H_DIM);
  prep_see<<<512, 256, 0, stream>>>(see, SEETT, SEEB8);
  gather_vecs<<<ROWS/4, 256, 0, stream>>>(emb, inp, VECSb);

  // ZV = pack(vecs, vecs @ see_top + bias)  — direct packed epilogue (MODE 5)
  gemm_bt<5><<<128*4, 256, 0, stream>>>(VECSb, SEETT, bias, nullptr, nullptr,
                                        VECSb, ZV, ROWS, F_DIM, F_DIM, 128, 4);

  // batch-parallel recurrence: 4 WGs, fp8-resident weights, no inter-block sync
  recurrence_batch<<<4, 512, 0, stream>>>(ZV, SEEB8, CONTB);

  // downstream
  ln_kernel<<<ROWS/4, 256, 0, stream>>>(CONTB, ln_g, ln_b, XLN);
  gemm_bt<0><<<128*16, 256, 0, stream>>>(XLN,  WINb,  b_in,  Hb,   nullptr,
                                         nullptr, nullptr, ROWS, H_DIM, F_DIM, 128, 16);
  gemm_bt<4><<<128*4,  256, 0, stream>>>(Hb,   WOUTb, b_out, OUTb, OUT8,
                                         nullptr, nullptr, ROWS, F_DIM, H_DIM, 128, 4);
  tlogit_kernel<<<ROWS/4, 256, 0, stream>>>(OUTb, EMBb, tgt, TL);
  gemm_f8_logits<<<128*NT_LOG, 256, 0, stream>>>(OUT8, EMB8, PART, ROWS, V_DIM, F_DIM, 128, NT_LOG);
  lse_kernel<<<ROWS/4, 256, 0, stream>>>(PART, TL, NLL);
  loss_kernel<<<1, 256, 0, stream>>>(NLL, tgt, (float*)d_out);
}

// Round 7
// 1146.656 us; speedup vs baseline: 1.2846x; 1.2846x over previous
//
#include <hip/hip_runtime.h>
#include <hip/hip_fp8.h>

#define F_DIM 512
#define H_DIM 2048
#define V_DIM 32000
#define B_DIM 64
#define S_DIM 256
#define ROWS (S_DIM*B_DIM)          // 16384
#define NT_LOG 250                  // 32000/128
#define SCALE 0.04419417382415922f  // 1/sqrt(512)
#define LSE_OFF 40.0f               // fixed softmax offset; |logit*SCALE| ~ O(8)

typedef __attribute__((ext_vector_type(8))) short  short8;
typedef __attribute__((ext_vector_type(4))) float  floatx4;
typedef __attribute__((ext_vector_type(4))) int    intx4;
typedef __attribute__((ext_vector_type(8))) int    i32x8;
typedef __attribute__((ext_vector_type(4))) unsigned int uix4;

static __device__ inline unsigned short f2bf(float x){
  unsigned int u = __float_as_uint(x);
  u += 0x7fffu + ((u >> 16) & 1u);           // RNE
  return (unsigned short)(u >> 16);
}
static __device__ inline float bf2f(unsigned short u){
  return __uint_as_float(((unsigned int)u) << 16);
}
static __device__ inline unsigned char f2fp8(float x){
  __hip_fp8_e4m3 q(x);
  return q.__x;
}
// fp8-buffer bank swizzle: within each 64-B segment of a row, granule g (8 B)
// is stored at chunk=(g>>1)^((row>>1)&3), lob=(g&1)^((row>>3)&1). With this,
// a 16-lane ds_read_b64 phase in gemm_f8_logits covers all 32 banks exactly
// once (r9 lesson: staging's 16-B atomicity forbids fixing lob at load time).
static __device__ inline int sw8(int row, int col){
  int g = (col >> 3) & 7;
  int chunk = ((g >> 1) ^ ((row >> 1) & 3));
  int lob = (g & 1) ^ ((row >> 3) & 1);
  return (col & ~63) | (chunk << 4) | (lob << 3) | (col & 7);
}
// ZV permutation within each 64-word group: col c -> (c&~63)|((c&15)<<2)|((c>>4)&3)
// so the recurrence thread (rl) reads its 4 words (tl=0..3) contiguously (dwordx4).
static __device__ inline int zvperm(int c){
  return (c & ~63) | ((c & 15) << 2) | ((c >> 4) & 3);
}
static __device__ inline float wsum(float v){
  #pragma unroll
  for(int m = 32; m > 0; m >>= 1) v += __shfl_xor(v, m);
  return v;
}
static __device__ inline void load_lds16(const void* g, void* l){
  __builtin_amdgcn_global_load_lds((const __attribute__((address_space(1))) void*)g,
                                   (__attribute__((address_space(3))) void*)l, 16, 0, 0);
}

// ---------------- casts ----------------
__global__ __launch_bounds__(256) void cast_w(const float* __restrict__ src,
                                              unsigned short* __restrict__ dst, int n){
  int i = blockIdx.x*256 + threadIdx.x;
  int stride = gridDim.x*256;
  for(; i < n; i += stride) dst[i] = f2bf(src[i]);
}
// emb -> bf16 (for tlogit) + fp8 bank-swizzled (for logits GEMM), PAD row zeroed
__global__ __launch_bounds__(256) void cast_emb(const float* __restrict__ src,
    unsigned short* __restrict__ dst, unsigned char* __restrict__ d8){
  int i = blockIdx.x*256 + threadIdx.x;
  int stride = gridDim.x*256;
  for(; i < V_DIM*F_DIM; i += stride){
    float v = (i < F_DIM) ? 0.f : src[i];
    dst[i] = f2bf(v);
    int row = i >> 9, col = i & 511;
    d8[(long)row*512 + sw8(row, col)] = f2fp8(v);
  }
}

// ---------------- prep: see_top^T bf16 (for Z gemm) + see_bot^T fp8 ----------
__global__ __launch_bounds__(256) void prep_see(const float* __restrict__ see,
    unsigned short* __restrict__ TT, unsigned char* __restrict__ B8){
  int n = blockIdx.x;
  for(int k = threadIdx.x; k < 512; k += 256){
    TT[n*512 + k] = f2bf(see[(long)k*512 + n]);
    B8[n*512 + k] = f2fp8(see[(long)(512+k)*512 + n]);
  }
}

// ---------------- gather embedding rows per (t,b), bf16; row = t*64+b -------
__global__ __launch_bounds__(256) void gather_vecs(const float* __restrict__ emb,
    const int* __restrict__ inp, unsigned short* __restrict__ V){
  long row = (long)blockIdx.x*4 + (threadIdx.x >> 6);
  int l = threadIdx.x & 63;
  int t = (int)(row >> 6), b = (int)(row & 63);
  int idx = inp[b*S_DIM + t];
  short8 o;
  if (idx == 0){
    #pragma unroll
    for(int i=0;i<8;i++) o[i] = 0;
  } else {
    const float* e = emb + (long)idx*F_DIM + l*8;
    float4 a = *(const float4*)e;
    float4 bq = *(const float4*)(e + 4);
    o[0]=(short)f2bf(a.x); o[1]=(short)f2bf(a.y); o[2]=(short)f2bf(a.z); o[3]=(short)f2bf(a.w);
    o[4]=(short)f2bf(bq.x);o[5]=(short)f2bf(bq.y);o[6]=(short)f2bf(bq.z);o[7]=(short)f2bf(bq.w);
  }
  *(short8*)(V + row*F_DIM + l*8) = o;
}

// ---------------- batch-parallel recurrence, fp8-resident weights ----------
// r10: raw s_barrier (lgkmcnt-only) — HIP __syncthreads drains vmcnt(0).
// r11: HW packed cvts + v_rcp sigmoid (epilogue was VALU-issue-bound).
// r13: MX-scaled fp8 K=128 MFMA (unit scales) + per-tl MFMA/epilogue
// interleave + permuted ZV layout (dwordx4 loads).
__global__ __launch_bounds__(512, 1) void recurrence_batch(
    const unsigned int* __restrict__ ZV,       // [16384][512] permuted groups (zvperm)
    const unsigned char* __restrict__ W8,      // seeBotT fp8 [n=512][k=512]
    unsigned short* __restrict__ CONTB)        // [256][64][512] bf16 state history
{
  __shared__ unsigned char stt[2][16][560];    // 560 = b128-aligned pad, uniform banks

  const int tid = threadIdx.x;
  const int w  = tid >> 6;       // wave 0..7 -> cols w*64..
  const int l  = tid & 63;
  const int rl = l & 15, rq = l >> 4;
  const int wg = blockIdx.x;     // batch rows wg*16..
  const int colb = w*64;

  // persistent fp8 B fragments for MX K=128: [k-tile][n-tile], 8 VGPRs each
  // col = colb+tl*16+rl, k = kt*128 + rq*32 .. +31
  i32x8 Bfr[4][4];
  #pragma unroll
  for(int kt=0;kt<4;kt++)
    #pragma unroll
    for(int tl=0;tl<4;tl++)
      Bfr[kt][tl] = *(const i32x8*)(W8 + (long)(colb + tl*16 + rl)*512 + kt*128 + rq*32);

  float s_old[16];
  #pragma unroll
  for(int i=0;i<16;i++) s_old[i] = 0.f;

  // per-thread ZV base: rows wg*16+rq*4+r, permuted words colb+rl*4 .. +3
  const unsigned int* zbase = ZV + (long)(wg*16 + rq*4)*512 + colb + rl*4;
  unsigned short* cbase = CONTB + ((long)wg*16 + rq*4)*512 + colb + rl;

  uix4 zv[4];
  #pragma unroll
  for(int r=0;r<4;r++) zv[r] = *(const uix4*)(zbase + (long)r*512);

  for(int t = 0; t < S_DIM; t++){
    // cross-wave visibility of prev-step LDS state: LDS ops only.
    asm volatile("s_waitcnt lgkmcnt(0)" ::: "memory");
    __builtin_amdgcn_s_barrier();
    asm volatile("" ::: "memory");   // no LDS-read hoisting above the barrier

    floatx4 acc[4];
    #pragma unroll
    for(int tl=0;tl<4;tl++) acc[tl] = (floatx4)0.f;

    i32x8 afr[4];
    if (t > 0){
      const unsigned char* sb = &stt[(t-1)&1][0][0] + rl*560 + rq*32;
      #pragma unroll
      for(int kt=0;kt<4;kt++){
        intx4 a0 = *(const intx4*)(sb + kt*128);
        intx4 a1 = *(const intx4*)(sb + kt*128 + 16);
        afr[kt] = __builtin_shufflevector(a0, a1, 0,1,2,3,4,5,6,7);
      }
    }

    unsigned short* cw = cbase + (long)t*64*512;
    unsigned char* swb = &stt[t&1][0][0] + rq*4*560 + colb + rl;

    #pragma unroll
    for(int tl=0;tl<4;tl++){
      if (t > 0){
        #pragma unroll
        for(int kt=0;kt<4;kt++)
          acc[tl] = __builtin_amdgcn_mfma_scale_f32_16x16x128_f8f6f4(
                        afr[kt], Bfr[kt][tl], acc[tl],
                        0, 0,                    // cbsz/blgp: fp8 e4m3 both
                        0, 0x7f7f7f7f,           // scale A opsel, value (2^0)
                        0, 0x7f7f7f7f);          // scale B opsel, value (2^0)
      }
      // epilogue for this tl overlaps the other tl chains' MFMA issue
      float sv[4];
      #pragma unroll
      for(int r=0;r<4;r++){
        unsigned int p = zv[r][tl];
        float z = __uint_as_float(p << 16) + acc[tl][r];       // bf2f(lo)
        float v = __uint_as_float(p & 0xffff0000u);            // bf2f(hi)
        float e = __expf(-z);
        float g = __builtin_amdgcn_rcpf(1.f + e);              // sigmoid
        float s = fmaf(s_old[tl*4+r] - v, g, v);
        s_old[tl*4+r] = s;
        sv[r] = s;
      }
      #pragma unroll
      for(int pr=0; pr<2; pr++){
        unsigned int bfp, f8p;
        asm("v_cvt_pk_bf16_f32 %0, %1, %2" : "=v"(bfp) : "v"(sv[pr*2]), "v"(sv[pr*2+1]));
        asm("v_cvt_pk_fp8_f32 %0, %1, %2"  : "=v"(f8p) : "v"(sv[pr*2]), "v"(sv[pr*2+1]));
        cw[(long)(pr*2)*512   + tl*16] = (unsigned short)(bfp & 0xffffu);
        cw[(long)(pr*2+1)*512 + tl*16] = (unsigned short)(bfp >> 16);
        swb[(pr*2)*560   + tl*16] = (unsigned char)(f8p & 0xffu);
        swb[(pr*2+1)*560 + tl*16] = (unsigned char)((f8p >> 8) & 0xffu);
      }
    }

    // load next step's ZV (WAR-ordered after last zv use; latency hides under
    // next step's barrier + MFMA chains; ZV is L3-resident)
    if (t+1 < S_DIM){
      const unsigned int* zp = zbase + (long)(t+1)*64*512;
      #pragma unroll
      for(int r=0;r<4;r++) zv[r] = *(const uix4*)(zp + (long)r*512);
    }
  }
}

// ---------------- layernorm (bf16 in) + bf16 cast; 1 row per wave ----------------
__global__ __launch_bounds__(256) void ln_kernel(const unsigned short* __restrict__ contb,
    const float* __restrict__ lg, const float* __restrict__ lb,
    unsigned short* __restrict__ xln)
{
  const int wid = threadIdx.x >> 6, l = threadIdx.x & 63;
  const long row = (long)blockIdx.x*4 + wid;
  short8 xv = *(const short8*)(contb + row*F_DIM + l*8);
  float v[8];
  #pragma unroll
  for(int i=0;i<8;i++) v[i] = bf2f((unsigned short)xv[i]);
  float s = 0.f;
  #pragma unroll
  for(int i=0;i<8;i++) s += v[i];
  s = wsum(s);
  float mu = s * (1.f/512.f);
  float q = 0.f;
  #pragma unroll
  for(int i=0;i<8;i++){ float d = v[i]-mu; q += d*d; }
  q = wsum(q);
  float rs = rsqrtf(q*(1.f/512.f) + 1e-5f);
  short8 o;
  #pragma unroll
  for(int i=0;i<8;i++)
    o[i] = (short)f2bf((v[i]-mu)*rs*lg[l*8+i] + lb[l*8+i]);
  *(short8*)(xln + row*F_DIM + l*8) = o;
}

// ---------------- bf16 MFMA GEMM: C[M,N] = A[M,K] * B[N,K]^T ----------------
// XOR-swizzled LDS (r6: conflicts 1.97e8 -> 0).
// MODE 0: +bias, relu, store bf16.
// MODE 4: +bias, store bf16 AND bank-swizzled fp8 (logits-GEMM input; N must be 512).
// MODE 5: +bias, store packed ZV word (vzperm'd col): (Vsrc<<16)|bf16(v).
template<int MODE>
__global__ __launch_bounds__(256) void gemm_bt(
    const unsigned short* __restrict__ A,
    const unsigned short* __restrict__ Bm,
    const float* __restrict__ bias,
    unsigned short* __restrict__ C,
    unsigned char* __restrict__ C8,
    const unsigned short* __restrict__ Vsrc,
    unsigned int* __restrict__ ZVout,
    int M, int N, int K, int tiles_m, int tiles_n)
{
  __shared__ short As[128*64];
  __shared__ short Bs[128*64];

  const int bid = blockIdx.x;
  const int mt = bid % tiles_m;
  const int nt = bid / tiles_m;
  const long m0 = (long)mt * 128;
  const long n0 = (long)nt * 128;
  const int tid = threadIdx.x;
  const int l = tid & 63;
  const int wid = tid >> 6;
  const int wr = wid >> 1, wc = wid & 1;
  const int rl = l & 15, rq = l >> 4;

  const short* Ag = (const short*)A + m0 * K;
  const short* Bg = (const short*)Bm + n0 * K;
  const int grow = tid >> 3;   // 0..31
  const int kp = tid & 7;      // 0..7
  const int ksw = (kp ^ (grow & 7)) * 8;   // swizzled global chunk offset (shorts)

  floatx4 acc[4][4];
  #pragma unroll
  for(int i=0;i<4;i++)
    #pragma unroll
    for(int j=0;j<4;j++) acc[i][j] = (floatx4)0.f;

  for(int k0 = 0; k0 < K; k0 += 64){
    __syncthreads();
    #pragma unroll
    for(int ro = 0; ro < 128; ro += 32){
      load_lds16(Ag + (long)(ro + grow)*K + k0 + ksw, (void*)(As + (ro+grow)*64 + kp*8));
      load_lds16(Bg + (long)(ro + grow)*K + k0 + ksw, (void*)(Bs + (ro+grow)*64 + kp*8));
    }
    __syncthreads();
    #pragma unroll
    for(int kb = 0; kb < 64; kb += 32){
      const int cb = kb >> 3;              // base chunk: 0 or 4
      const int cl = ((cb + rq) ^ (rl & 7)) * 8;   // swizzled LDS chunk (shorts)
      short8 af[4], bfr[4];
      #pragma unroll
      for(int i=0;i<4;i++) af[i]  = *(const short8*)(As + (wr*64 + i*16 + rl)*64 + cl);
      #pragma unroll
      for(int j=0;j<4;j++) bfr[j] = *(const short8*)(Bs + (wc*64 + j*16 + rl)*64 + cl);
      #pragma unroll
      for(int i=0;i<4;i++)
        #pragma unroll
        for(int j=0;j<4;j++)
          acc[i][j] = __builtin_amdgcn_mfma_f32_16x16x32_bf16(af[i], bfr[j], acc[i][j], 0, 0, 0);
    }
  }

  const long mb = m0 + wr*64;
  const long nb = n0 + wc*64;
  #pragma unroll
  for(int j=0;j<4;j++){
    float bj = bias[nb + j*16 + rl];
    #pragma unroll
    for(int i=0;i<4;i++){
      #pragma unroll
      for(int r=0;r<4;r++){
        float v = acc[i][j][r] + bj;
        if (MODE == 0) v = fmaxf(v, 0.f);
        int rowI = (int)(mb + i*16 + rq*4 + r);
        int colI = (int)(nb + j*16 + rl);
        long idx = (long)rowI*N + colI;
        if (MODE == 5){
          ZVout[(long)rowI*N + zvperm(colI)] =
              ((unsigned)Vsrc[idx] << 16) | (unsigned)f2bf(v);
        } else {
          C[idx] = f2bf(v);
          if (MODE == 4) C8[(long)rowI*512 + sw8(rowI, colI)] = f2fp8(v);
        }
      }
    }
  }
}

// ---------------- fp8 logits GEMM + fixed-offset softmax partials ----------
// Inputs PRE-BANK-SWIZZLED (sw8); staging identity; zero LDS conflicts.
// r12 (T3+T4+T5): counted-vmcnt double-buffer pipeline — the proven 512 µs
// structure (MfmaUtil 47%). r14/r15 MX variants both regressed (occupancy /
// divergent-fragment codegen); REVERTED.
// r16: sm2 aliases As8 (dead after K-loop; in-loop lgkmcnt(0)+barrier means
// all As8 reads retired) -> LDS 33792->32768 B -> 5 blocks/CU (was 4), +25%
// cross-block TLP to fill the phase gaps.
__global__ __launch_bounds__(256) void gemm_f8_logits(
    const unsigned char* __restrict__ A8,
    const unsigned char* __restrict__ B8,
    float* __restrict__ part,
    int M, int N, int K, int tiles_m, int tiles_n)
{
  __shared__ unsigned char As8[2][128*64];
  __shared__ unsigned char Bs8[2][128*64];
  float (*sm2)[64][2] = (float(*)[64][2])&As8[0][0];   // alias: As8 dead post-loop

  const int bid = blockIdx.x;
  const int mt = bid % tiles_m;
  const int nt = bid / tiles_m;
  const long m0 = (long)mt * 128;
  const long n0 = (long)nt * 128;
  const int tid = threadIdx.x;
  const int l = tid & 63;
  const int wid = tid >> 6;
  const int wr = wid >> 1, wc = wid & 1;
  const int rl = l & 15, rq = l >> 4;

  const unsigned char* Ag = A8 + m0 * K;
  const unsigned char* Bg = B8 + n0 * K;
  const int grow = tid >> 2;               // 0..63
  const int kp = tid & 3;                  // 0..3

  floatx4 acc[4][4];
  #pragma unroll
  for(int i=0;i<4;i++)
    #pragma unroll
    for(int j=0;j<4;j++) acc[i][j] = (floatx4)0.f;

  // per-lane read swizzle pieces (row bits come from rl only; wave/tile bases
  // are multiples of 16 so their bits 1..3 contributions vanish)
  const int rsw = (rl >> 1) & 3;
  const int rhi = (rl >> 3) & 1;

  const int nkt = K >> 6;                  // 8 K-tiles of 64

  // stage K-tile kk into buffer bb (4 global_load_lds / thread)
  #define STAGE_F8(bb, kk) do {                                               \
    const long kof = (long)(kk)*64 + kp*16;                                   \
    load_lds16(Ag + (long)grow*K       + kof, (void*)(&As8[bb][grow*64       + kp*16])); \
    load_lds16(Ag + (long)(64+grow)*K  + kof, (void*)(&As8[bb][(64+grow)*64  + kp*16])); \
    load_lds16(Bg + (long)grow*K       + kof, (void*)(&Bs8[bb][grow*64       + kp*16])); \
    load_lds16(Bg + (long)(64+grow)*K  + kof, (void*)(&Bs8[bb][(64+grow)*64  + kp*16])); \
  } while(0)

  STAGE_F8(0, 0);
  STAGE_F8(1, 1);

  for(int t = 0; t < nkt; t++){
    // tile t staged (t+1's 4 loads may remain in flight)
    if (t < nkt-1) asm volatile("s_waitcnt vmcnt(4)" ::: "memory");
    else           asm volatile("s_waitcnt vmcnt(0)" ::: "memory");
    __builtin_amdgcn_s_barrier();
    __builtin_amdgcn_sched_barrier(0);

    const unsigned char* Abuf = &As8[t & 1][0];
    const unsigned char* Bbuf = &Bs8[t & 1][0];
    long af[2][4], bfr[2][4];
    #pragma unroll
    for(int kb = 0; kb < 2; kb++){
      const int g = (kb << 2) + rq;                  // logical granule 0..7
      const int cl = ((((g >> 1) ^ rsw)) << 4) | ((((g & 1) ^ rhi)) << 3);
      #pragma unroll
      for(int i=0;i<4;i++) af[kb][i]  = *(const long*)(Abuf + (wr*64 + i*16 + rl)*64 + cl);
      #pragma unroll
      for(int j=0;j<4;j++) bfr[kb][j] = *(const long*)(Bbuf + (wc*64 + j*16 + rl)*64 + cl);
    }
    asm volatile("s_waitcnt lgkmcnt(0)" ::: "memory");
    __builtin_amdgcn_sched_barrier(0);
    __builtin_amdgcn_s_barrier();                    // all reads done: buffer free
    __builtin_amdgcn_sched_barrier(0);

    if (t+2 < nkt) STAGE_F8(t & 1, t+2);             // async refill, 2 iters of flight

    __builtin_amdgcn_s_setprio(1);
    #pragma unroll
    for(int kb = 0; kb < 2; kb++)
      #pragma unroll
      for(int i=0;i<4;i++)
        #pragma unroll
        for(int j=0;j<4;j++)
          acc[i][j] = __builtin_amdgcn_mfma_f32_16x16x32_fp8_fp8(af[kb][i], bfr[kb][j], acc[i][j], 0, 0, 0);
    __builtin_amdgcn_s_setprio(0);
  }
  #undef STAGE_F8

  // fixed-offset sum-exp partials per 128-col tile (sm2 lives in As8 space;
  // all As8 ds_reads retired at the last in-loop lgkmcnt(0)+barrier)
  #pragma unroll
  for(int i=0;i<4;i++){
    #pragma unroll
    for(int r=0;r<4;r++){
      float sv = 0.f;
      #pragma unroll
      for(int j=0;j<4;j++) sv += __expf(acc[i][j][r]*SCALE - LSE_OFF);
      #pragma unroll
      for(int d=1; d<16; d<<=1) sv += __shfl_xor(sv, d);
      if (rl == 0) sm2[wr][i*16 + rq*4 + r][wc] = sv;
    }
  }
  __syncthreads();
  if (tid < 128){
    int wr2 = tid >> 6, rowl = tid & 63;
    part[(m0 + wr2*64 + rowl)*tiles_n + nt] = sm2[wr2][rowl][0] + sm2[wr2][rowl][1];
  }
}

// ---------------- target logit (bf16 inputs) ----------------
__global__ __launch_bounds__(256) void tlogit_kernel(const unsigned short* __restrict__ outb,
    const unsigned short* __restrict__ embb, const int* __restrict__ tgt,
    float* __restrict__ TL)
{
  long gw = (long)blockIdx.x*4 + (threadIdx.x >> 6);
  int l = threadIdx.x & 63;
  int t = (int)(gw >> 6), b = (int)(gw & 63);
  int tg = tgt[b*S_DIM + t];
  const unsigned short* o = outb + gw*F_DIM;
  const unsigned short* e = embb + (long)tg*F_DIM;
  short8 ov = *(const short8*)(o + l*8);
  short8 ev = *(const short8*)(e + l*8);
  float s = 0.f;
  #pragma unroll
  for(int i=0;i<8;i++) s += bf2f((unsigned short)ov[i]) * bf2f((unsigned short)ev[i]);
  s = wsum(s);
  if (l == 0) TL[gw] = s * SCALE;
}

// ---------------- sum partials -> nll ----------------
__global__ __launch_bounds__(256) void lse_kernel(const float* __restrict__ part,
    const float* __restrict__ TL, float* __restrict__ nll)
{
  long row = (long)blockIdx.x*4 + (threadIdx.x >> 6);
  int l = threadIdx.x & 63;
  float S = 0.f;
  for(int c = l; c < NT_LOG; c += 64)
    S += part[row*NT_LOG + c];
  S = wsum(S);
  if (l == 0) nll[row] = (LSE_OFF + logf(S)) - TL[row];
}

// ---------------- final loss ----------------
__global__ __launch_bounds__(256) void loss_kernel(const float* __restrict__ nll,
    const int* __restrict__ tgt, float* __restrict__ out)
{
  int t = threadIdx.x;
  float s = 0.f; int cnt = 0;
  for(int b = 0; b < B_DIM; b++){
    int v = tgt[b*S_DIM + t];
    if (v != 0){ s += nll[(long)t*B_DIM + b]; cnt++; }
  }
  float li = s / fmaxf((float)cnt, 1.f);
  li = wsum(li);
  __shared__ float red[4];
  if ((t & 63) == 0) red[t >> 6] = li;
  __syncthreads();
  if (t == 0) out[0] = (red[0]+red[1]+red[2]+red[3]) * (1.f/256.f);
}

extern "C" void kernel_launch(void* const* d_in, const int* in_sizes, int n_in,
                              void* d_out, int out_size, void* d_ws, size_t ws_size,
                              hipStream_t stream)
{
  const int*   inp   = (const int*)d_in[0];
  const int*   tgt   = (const int*)d_in[1];
  const float* see   = (const float*)d_in[2];
  const float* bias  = (const float*)d_in[3];
  const float* W_in  = (const float*)d_in[4];
  const float* b_in  = (const float*)d_in[5];
  const float* W_out = (const float*)d_in[6];
  const float* b_out = (const float*)d_in[7];
  const float* ln_g  = (const float*)d_in[8];
  const float* ln_b  = (const float*)d_in[9];
  const float* emb   = (const float*)d_in[10];

  // Workspace plan — peak ~205 MB. Aliases safe by stream order:
  //   XLN  aliases ZV     (ZV dead after recurrence; XLN born at ln)
  //   OUT8 aliases VECSb  (VECSb dead after Z-gemm; OUT8 born at FFN2)
  //   PART aliases Hb     (Hb dead after FFN2; PART born at logits gemm)
  char* p = (char*)d_ws;
  unsigned short* CONTB= (unsigned short*)p; p += (size_t)ROWS*F_DIM*2;   // 16.8 MB
  unsigned short* Hb   = (unsigned short*)p; p += (size_t)ROWS*H_DIM*2;   // 67.1 MB
  unsigned short* OUTb = (unsigned short*)p; p += (size_t)ROWS*F_DIM*2;   // 16.8 MB
  unsigned short* EMBb = (unsigned short*)p; p += (size_t)V_DIM*F_DIM*2;  // 32.8 MB
  unsigned char* EMB8  = (unsigned char*)p;  p += (size_t)V_DIM*F_DIM;    // 16.4 MB
  unsigned short* WINb = (unsigned short*)p; p += (size_t)H_DIM*F_DIM*2;  //  2.1 MB
  unsigned short* WOUTb= (unsigned short*)p; p += (size_t)F_DIM*H_DIM*2;  //  2.1 MB
  float* TL            = (float*)p;          p += (size_t)ROWS*4;
  float* NLL           = (float*)p;          p += (size_t)ROWS*4;
  unsigned short* VECSb= (unsigned short*)p; p += (size_t)ROWS*F_DIM*2;   // 16.8 MB
  unsigned int* ZV     = (unsigned int*)p;   p += (size_t)ROWS*F_DIM*4;   // 33.6 MB
  unsigned short* SEETT= (unsigned short*)p; p += (size_t)F_DIM*F_DIM*2;  //  0.5 MB
  unsigned char* SEEB8 = (unsigned char*)p;  p += (size_t)F_DIM*F_DIM;    //  0.26 MB
  // aliases
  unsigned short* XLN  = (unsigned short*)ZV;      // 16.8 of 33.6 MB
  unsigned char* OUT8  = (unsigned char*)VECSb;    //  8.4 of 16.8 MB
  float* PART          = (float*)Hb;               // 16.4 of 67.1 MB

  // independent prep
  cast_emb<<<4096, 256, 0, stream>>>(emb, EMBb, EMB8);
  cast_w<<<2048, 256, 0, stream>>>(W_in,  WINb,  H_DIM*F_DIM);
  cast_w<<<2048, 256, 0, stream>>>(W_out, WOUTb, F_DIM*H_DIM);
  prep_see<<<512, 256, 0, stream>>>(see, SEETT, SEEB8);
  gather_vecs<<<ROWS/4, 256, 0, stream>>>(emb, inp, VECSb);

  // ZV = pack(vecs, vecs @ see_top + bias)  — direct packed epilogue (MODE 5)
  gemm_bt<5><<<128*4, 256, 0, stream>>>(VECSb, SEETT, bias, nullptr, nullptr,
                                        VECSb, ZV, ROWS, F_DIM, F_DIM, 128, 4);

  // batch-parallel recurrence: 4 WGs, fp8-resident weights, no inter-block sync
  recurrence_batch<<<4, 512, 0, stream>>>(ZV, SEEB8, CONTB);

  // downstream
  ln_kernel<<<ROWS/4, 256, 0, stream>>>(CONTB, ln_g, ln_b, XLN);
  gemm_bt<0><<<128*16, 256, 0, stream>>>(XLN,  WINb,  b_in,  Hb,   nullptr,
                                         nullptr, nullptr, ROWS, H_DIM, F_DIM, 128, 16);
  gemm_bt<4><<<128*4,  256, 0, stream>>>(Hb,   WOUTb, b_out, OUTb, OUT8,
                                         nullptr, nullptr, ROWS, F_DIM, H_DIM, 128, 4);
  tlogit_kernel<<<ROWS/4, 256, 0, stream>>>(OUTb, EMBb, tgt, TL);
  gemm_f8_logits<<<128*NT_LOG, 256, 0, stream>>>(OUT8, EMB8, PART, ROWS, V_DIM, F_DIM, 128, NT_LOG);
  lse_kernel<<<ROWS/4, 256, 0, stream>>>(PART, TL, NLL);
  loss_kernel<<<1, 256, 0, stream>>>(NLL, tgt, (float*)d_out);
}

// Round 8
// 1125.770 us; speedup vs baseline: 1.3084x; 1.0186x over previous
//
#include <hip/hip_runtime.h>
#include <hip/hip_fp8.h>

#define F_DIM 512
#define H_DIM 2048
#define V_DIM 32000
#define B_DIM 64
#define S_DIM 256
#define ROWS (S_DIM*B_DIM)          // 16384
#define NT_LOG 250                  // 32000/128
#define SCALE 0.04419417382415922f  // 1/sqrt(512)
#define LSE_OFF 40.0f               // fixed softmax offset; |logit*SCALE| ~ O(8)

typedef __attribute__((ext_vector_type(8))) short  short8;
typedef __attribute__((ext_vector_type(4))) float  floatx4;
typedef __attribute__((ext_vector_type(4))) int    intx4;
typedef __attribute__((ext_vector_type(8))) int    i32x8;
typedef __attribute__((ext_vector_type(4))) unsigned int uix4;

static __device__ inline unsigned short f2bf(float x){
  unsigned int u = __float_as_uint(x);
  u += 0x7fffu + ((u >> 16) & 1u);           // RNE
  return (unsigned short)(u >> 16);
}
static __device__ inline float bf2f(unsigned short u){
  return __uint_as_float(((unsigned int)u) << 16);
}
static __device__ inline unsigned char f2fp8(float x){
  __hip_fp8_e4m3 q(x);
  return q.__x;
}
// fp8-buffer bank swizzle: within each 64-B segment of a row, granule g (8 B)
// is stored at chunk=(g>>1)^((row>>1)&3), lob=(g&1)^((row>>3)&1). With this,
// a 16-lane ds_read_b64 phase in gemm_f8_logits covers all 32 banks exactly
// once (r9 lesson: staging's 16-B atomicity forbids fixing lob at load time).
static __device__ inline int sw8(int row, int col){
  int g = (col >> 3) & 7;
  int chunk = ((g >> 1) ^ ((row >> 1) & 3));
  int lob = (g & 1) ^ ((row >> 3) & 1);
  return (col & ~63) | (chunk << 4) | (lob << 3) | (col & 7);
}
// ZV permutation within each 64-word group: col c -> (c&~63)|((c&15)<<2)|((c>>4)&3)
// so the recurrence thread (rl) reads its 4 words (tl=0..3) contiguously (dwordx4).
static __device__ inline int zvperm(int c){
  return (c & ~63) | ((c & 15) << 2) | ((c >> 4) & 3);
}
static __device__ inline float wsum(float v){
  #pragma unroll
  for(int m = 32; m > 0; m >>= 1) v += __shfl_xor(v, m);
  return v;
}
static __device__ inline void load_lds16(const void* g, void* l){
  __builtin_amdgcn_global_load_lds((const __attribute__((address_space(1))) void*)g,
                                   (__attribute__((address_space(3))) void*)l, 16, 0, 0);
}

// ---------------- casts ----------------
__global__ __launch_bounds__(256) void cast_w(const float* __restrict__ src,
                                              unsigned short* __restrict__ dst, int n){
  int i = blockIdx.x*256 + threadIdx.x;
  int stride = gridDim.x*256;
  for(; i < n; i += stride) dst[i] = f2bf(src[i]);
}
// emb -> bf16 (for tlogit) + fp8 bank-swizzled (for logits GEMM), PAD row zeroed
__global__ __launch_bounds__(256) void cast_emb(const float* __restrict__ src,
    unsigned short* __restrict__ dst, unsigned char* __restrict__ d8){
  int i = blockIdx.x*256 + threadIdx.x;
  int stride = gridDim.x*256;
  for(; i < V_DIM*F_DIM; i += stride){
    float v = (i < F_DIM) ? 0.f : src[i];
    dst[i] = f2bf(v);
    int row = i >> 9, col = i & 511;
    d8[(long)row*512 + sw8(row, col)] = f2fp8(v);
  }
}

// ---------------- prep: see_top^T bf16 (for Z gemm) + see_bot^T fp8 ----------
__global__ __launch_bounds__(256) void prep_see(const float* __restrict__ see,
    unsigned short* __restrict__ TT, unsigned char* __restrict__ B8){
  int n = blockIdx.x;
  for(int k = threadIdx.x; k < 512; k += 256){
    TT[n*512 + k] = f2bf(see[(long)k*512 + n]);
    B8[n*512 + k] = f2fp8(see[(long)(512+k)*512 + n]);
  }
}

// ---------------- gather embedding rows per (t,b), bf16; row = t*64+b -------
__global__ __launch_bounds__(256) void gather_vecs(const float* __restrict__ emb,
    const int* __restrict__ inp, unsigned short* __restrict__ V){
  long row = (long)blockIdx.x*4 + (threadIdx.x >> 6);
  int l = threadIdx.x & 63;
  int t = (int)(row >> 6), b = (int)(row & 63);
  int idx = inp[b*S_DIM + t];
  short8 o;
  if (idx == 0){
    #pragma unroll
    for(int i=0;i<8;i++) o[i] = 0;
  } else {
    const float* e = emb + (long)idx*F_DIM + l*8;
    float4 a = *(const float4*)e;
    float4 bq = *(const float4*)(e + 4);
    o[0]=(short)f2bf(a.x); o[1]=(short)f2bf(a.y); o[2]=(short)f2bf(a.z); o[3]=(short)f2bf(a.w);
    o[4]=(short)f2bf(bq.x);o[5]=(short)f2bf(bq.y);o[6]=(short)f2bf(bq.z);o[7]=(short)f2bf(bq.w);
  }
  *(short8*)(V + row*F_DIM + l*8) = o;
}

// ---------------- batch-parallel recurrence, fp8-resident weights ----------
// r10: raw s_barrier (lgkmcnt-only) — HIP __syncthreads drains vmcnt(0).
// r11: HW packed cvts + v_rcp sigmoid (epilogue was VALU-issue-bound).
// r13: MX-scaled fp8 K=128 MFMA (unit scales) + per-tl MFMA/epilogue
// interleave + permuted ZV layout (dwordx4 loads).
__global__ __launch_bounds__(512, 1) void recurrence_batch(
    const unsigned int* __restrict__ ZV,       // [16384][512] permuted groups (zvperm)
    const unsigned char* __restrict__ W8,      // seeBotT fp8 [n=512][k=512]
    unsigned short* __restrict__ CONTB)        // [256][64][512] bf16 state history
{
  __shared__ unsigned char stt[2][16][560];    // 560 = b128-aligned pad, uniform banks

  const int tid = threadIdx.x;
  const int w  = tid >> 6;       // wave 0..7 -> cols w*64..
  const int l  = tid & 63;
  const int rl = l & 15, rq = l >> 4;
  const int wg = blockIdx.x;     // batch rows wg*16..
  const int colb = w*64;

  // persistent fp8 B fragments for MX K=128: [k-tile][n-tile], 8 VGPRs each
  // col = colb+tl*16+rl, k = kt*128 + rq*32 .. +31
  i32x8 Bfr[4][4];
  #pragma unroll
  for(int kt=0;kt<4;kt++)
    #pragma unroll
    for(int tl=0;tl<4;tl++)
      Bfr[kt][tl] = *(const i32x8*)(W8 + (long)(colb + tl*16 + rl)*512 + kt*128 + rq*32);

  float s_old[16];
  #pragma unroll
  for(int i=0;i<16;i++) s_old[i] = 0.f;

  // per-thread ZV base: rows wg*16+rq*4+r, permuted words colb+rl*4 .. +3
  const unsigned int* zbase = ZV + (long)(wg*16 + rq*4)*512 + colb + rl*4;
  unsigned short* cbase = CONTB + ((long)wg*16 + rq*4)*512 + colb + rl;

  uix4 zv[4];
  #pragma unroll
  for(int r=0;r<4;r++) zv[r] = *(const uix4*)(zbase + (long)r*512);

  for(int t = 0; t < S_DIM; t++){
    // cross-wave visibility of prev-step LDS state: LDS ops only.
    asm volatile("s_waitcnt lgkmcnt(0)" ::: "memory");
    __builtin_amdgcn_s_barrier();
    asm volatile("" ::: "memory");   // no LDS-read hoisting above the barrier

    floatx4 acc[4];
    #pragma unroll
    for(int tl=0;tl<4;tl++) acc[tl] = (floatx4)0.f;

    i32x8 afr[4];
    if (t > 0){
      const unsigned char* sb = &stt[(t-1)&1][0][0] + rl*560 + rq*32;
      #pragma unroll
      for(int kt=0;kt<4;kt++){
        intx4 a0 = *(const intx4*)(sb + kt*128);
        intx4 a1 = *(const intx4*)(sb + kt*128 + 16);
        afr[kt] = __builtin_shufflevector(a0, a1, 0,1,2,3,4,5,6,7);
      }
    }

    unsigned short* cw = cbase + (long)t*64*512;
    unsigned char* swb = &stt[t&1][0][0] + rq*4*560 + colb + rl;

    #pragma unroll
    for(int tl=0;tl<4;tl++){
      if (t > 0){
        #pragma unroll
        for(int kt=0;kt<4;kt++)
          acc[tl] = __builtin_amdgcn_mfma_scale_f32_16x16x128_f8f6f4(
                        afr[kt], Bfr[kt][tl], acc[tl],
                        0, 0,                    // cbsz/blgp: fp8 e4m3 both
                        0, 0x7f7f7f7f,           // scale A opsel, value (2^0)
                        0, 0x7f7f7f7f);          // scale B opsel, value (2^0)
      }
      // epilogue for this tl overlaps the other tl chains' MFMA issue
      float sv[4];
      #pragma unroll
      for(int r=0;r<4;r++){
        unsigned int p = zv[r][tl];
        float z = __uint_as_float(p << 16) + acc[tl][r];       // bf2f(lo)
        float v = __uint_as_float(p & 0xffff0000u);            // bf2f(hi)
        float e = __expf(-z);
        float g = __builtin_amdgcn_rcpf(1.f + e);              // sigmoid
        float s = fmaf(s_old[tl*4+r] - v, g, v);
        s_old[tl*4+r] = s;
        sv[r] = s;
      }
      #pragma unroll
      for(int pr=0; pr<2; pr++){
        unsigned int bfp, f8p;
        asm("v_cvt_pk_bf16_f32 %0, %1, %2" : "=v"(bfp) : "v"(sv[pr*2]), "v"(sv[pr*2+1]));
        asm("v_cvt_pk_fp8_f32 %0, %1, %2"  : "=v"(f8p) : "v"(sv[pr*2]), "v"(sv[pr*2+1]));
        cw[(long)(pr*2)*512   + tl*16] = (unsigned short)(bfp & 0xffffu);
        cw[(long)(pr*2+1)*512 + tl*16] = (unsigned short)(bfp >> 16);
        swb[(pr*2)*560   + tl*16] = (unsigned char)(f8p & 0xffu);
        swb[(pr*2+1)*560 + tl*16] = (unsigned char)((f8p >> 8) & 0xffu);
      }
    }

    // load next step's ZV (WAR-ordered after last zv use; latency hides under
    // next step's barrier + MFMA chains; ZV is L3-resident)
    if (t+1 < S_DIM){
      const unsigned int* zp = zbase + (long)(t+1)*64*512;
      #pragma unroll
      for(int r=0;r<4;r++) zv[r] = *(const uix4*)(zp + (long)r*512);
    }
  }
}

// ---------------- layernorm (bf16 in) + bf16 cast; 1 row per wave ----------------
__global__ __launch_bounds__(256) void ln_kernel(const unsigned short* __restrict__ contb,
    const float* __restrict__ lg, const float* __restrict__ lb,
    unsigned short* __restrict__ xln)
{
  const int wid = threadIdx.x >> 6, l = threadIdx.x & 63;
  const long row = (long)blockIdx.x*4 + wid;
  short8 xv = *(const short8*)(contb + row*F_DIM + l*8);
  float v[8];
  #pragma unroll
  for(int i=0;i<8;i++) v[i] = bf2f((unsigned short)xv[i]);
  float s = 0.f;
  #pragma unroll
  for(int i=0;i<8;i++) s += v[i];
  s = wsum(s);
  float mu = s * (1.f/512.f);
  float q = 0.f;
  #pragma unroll
  for(int i=0;i<8;i++){ float d = v[i]-mu; q += d*d; }
  q = wsum(q);
  float rs = rsqrtf(q*(1.f/512.f) + 1e-5f);
  short8 o;
  #pragma unroll
  for(int i=0;i<8;i++)
    o[i] = (short)f2bf((v[i]-mu)*rs*lg[l*8+i] + lb[l*8+i]);
  *(short8*)(xln + row*F_DIM + l*8) = o;
}

// ---------------- bf16 MFMA GEMM: C[M,N] = A[M,K] * B[N,K]^T ----------------
// XOR-swizzled LDS (r6: conflicts 1.97e8 -> 0).
// MODE 0: +bias, relu, store bf16.
// MODE 4: +bias, store bf16 AND bank-swizzled fp8 (logits-GEMM input; N must be 512).
// MODE 5: +bias, store packed ZV word (vzperm'd col): (Vsrc<<16)|bf16(v).
template<int MODE>
__global__ __launch_bounds__(256) void gemm_bt(
    const unsigned short* __restrict__ A,
    const unsigned short* __restrict__ Bm,
    const float* __restrict__ bias,
    unsigned short* __restrict__ C,
    unsigned char* __restrict__ C8,
    const unsigned short* __restrict__ Vsrc,
    unsigned int* __restrict__ ZVout,
    int M, int N, int K, int tiles_m, int tiles_n)
{
  __shared__ short As[128*64];
  __shared__ short Bs[128*64];

  const int bid = blockIdx.x;
  const int mt = bid % tiles_m;
  const int nt = bid / tiles_m;
  const long m0 = (long)mt * 128;
  const long n0 = (long)nt * 128;
  const int tid = threadIdx.x;
  const int l = tid & 63;
  const int wid = tid >> 6;
  const int wr = wid >> 1, wc = wid & 1;
  const int rl = l & 15, rq = l >> 4;

  const short* Ag = (const short*)A + m0 * K;
  const short* Bg = (const short*)Bm + n0 * K;
  const int grow = tid >> 3;   // 0..31
  const int kp = tid & 7;      // 0..7
  const int ksw = (kp ^ (grow & 7)) * 8;   // swizzled global chunk offset (shorts)

  floatx4 acc[4][4];
  #pragma unroll
  for(int i=0;i<4;i++)
    #pragma unroll
    for(int j=0;j<4;j++) acc[i][j] = (floatx4)0.f;

  for(int k0 = 0; k0 < K; k0 += 64){
    __syncthreads();
    #pragma unroll
    for(int ro = 0; ro < 128; ro += 32){
      load_lds16(Ag + (long)(ro + grow)*K + k0 + ksw, (void*)(As + (ro+grow)*64 + kp*8));
      load_lds16(Bg + (long)(ro + grow)*K + k0 + ksw, (void*)(Bs + (ro+grow)*64 + kp*8));
    }
    __syncthreads();
    #pragma unroll
    for(int kb = 0; kb < 64; kb += 32){
      const int cb = kb >> 3;              // base chunk: 0 or 4
      const int cl = ((cb + rq) ^ (rl & 7)) * 8;   // swizzled LDS chunk (shorts)
      short8 af[4], bfr[4];
      #pragma unroll
      for(int i=0;i<4;i++) af[i]  = *(const short8*)(As + (wr*64 + i*16 + rl)*64 + cl);
      #pragma unroll
      for(int j=0;j<4;j++) bfr[j] = *(const short8*)(Bs + (wc*64 + j*16 + rl)*64 + cl);
      #pragma unroll
      for(int i=0;i<4;i++)
        #pragma unroll
        for(int j=0;j<4;j++)
          acc[i][j] = __builtin_amdgcn_mfma_f32_16x16x32_bf16(af[i], bfr[j], acc[i][j], 0, 0, 0);
    }
  }

  const long mb = m0 + wr*64;
  const long nb = n0 + wc*64;
  #pragma unroll
  for(int j=0;j<4;j++){
    float bj = bias[nb + j*16 + rl];
    #pragma unroll
    for(int i=0;i<4;i++){
      #pragma unroll
      for(int r=0;r<4;r++){
        float v = acc[i][j][r] + bj;
        if (MODE == 0) v = fmaxf(v, 0.f);
        int rowI = (int)(mb + i*16 + rq*4 + r);
        int colI = (int)(nb + j*16 + rl);
        long idx = (long)rowI*N + colI;
        if (MODE == 5){
          ZVout[(long)rowI*N + zvperm(colI)] =
              ((unsigned)Vsrc[idx] << 16) | (unsigned)f2bf(v);
        } else {
          C[idx] = f2bf(v);
          if (MODE == 4) C8[(long)rowI*512 + sw8(rowI, colI)] = f2fp8(v);
        }
      }
    }
  }
}

// ---------------- fp8 logits GEMM + fixed-offset softmax partials ----------
// Inputs PRE-BANK-SWIZZLED (sw8); staging identity; zero LDS conflicts.
// r12 (T3+T4+T5): counted-vmcnt double-buffer pipeline (proven 512 µs).
// r16: sm2 aliases As8 (dead after K-loop).
// r17: counters showed MfmaUtil 46% + VALUBusy 49% ~ saturation; the VALU is
// per-tile LDS address recomputation (sched_barrier blocks LICM). All 16
// ds_read addresses are lane constants + buffer parity: precompute 16 VGPR
// addresses for buffer 0, emit inline-asm ds_read_b64 with the parity as an
// offset:8192 IMMEDIATE, unroll K-loop x2 (even/odd tile). Per-tile LDS
// addressing VALU -> 0.
__global__ __launch_bounds__(256) void gemm_f8_logits(
    const unsigned char* __restrict__ A8,
    const unsigned char* __restrict__ B8,
    float* __restrict__ part,
    int M, int N, int K, int tiles_m, int tiles_n)
{
  __shared__ unsigned char As8[2][128*64];
  __shared__ unsigned char Bs8[2][128*64];
  float (*sm2)[64][2] = (float(*)[64][2])&As8[0][0];   // alias: As8 dead post-loop

  const int bid = blockIdx.x;
  const int mt = bid % tiles_m;
  const int nt = bid / tiles_m;
  const long m0 = (long)mt * 128;
  const long n0 = (long)nt * 128;
  const int tid = threadIdx.x;
  const int l = tid & 63;
  const int wid = tid >> 6;
  const int wr = wid >> 1, wc = wid & 1;
  const int rl = l & 15, rq = l >> 4;

  const unsigned char* Ag = A8 + m0 * K;
  const unsigned char* Bg = B8 + n0 * K;
  const int grow = tid >> 2;               // 0..63
  const int kp = tid & 3;                  // 0..3

  floatx4 acc[4][4];
  #pragma unroll
  for(int i=0;i<4;i++)
    #pragma unroll
    for(int j=0;j<4;j++) acc[i][j] = (floatx4)0.f;

  // ---- precomputed per-lane LDS byte addresses (buffer 0) -----------------
  // read (kb, row): addr = base + row*64 + cl[kb]; buffer 1 = +8192 immediate.
  const int rsw = (rl >> 1) & 3;
  const int rhi = (rl >> 3) & 1;
  unsigned adrA[2][4], adrB[2][4];
  {
    unsigned baseA = (unsigned)(size_t)(__attribute__((address_space(3))) char*)&As8[0][0];
    unsigned baseB = (unsigned)(size_t)(__attribute__((address_space(3))) char*)&Bs8[0][0];
    #pragma unroll
    for(int kb=0; kb<2; kb++){
      int g = (kb << 2) + rq;
      int cl = ((((g >> 1) ^ rsw)) << 4) | (((g & 1) ^ rhi) << 3);
      #pragma unroll
      for(int i=0;i<4;i++) adrA[kb][i] = baseA + (unsigned)((wr*64 + i*16 + rl)*64 + cl);
      #pragma unroll
      for(int j=0;j<4;j++) adrB[kb][j] = baseB + (unsigned)((wc*64 + j*16 + rl)*64 + cl);
    }
  }
  #define DSRD0(dst, adr) asm volatile("ds_read_b64 %0, %1"             : "=v"(dst) : "v"(adr))
  #define DSRD1(dst, adr) asm volatile("ds_read_b64 %0, %1 offset:8192" : "=v"(dst) : "v"(adr))

  const int nkt = K >> 6;                  // 8 K-tiles of 64 (must be even)

  // stage K-tile kk into buffer bb (4 global_load_lds / thread)
  #define STAGE_F8(bb, kk) do {                                               \
    const long kof = (long)(kk)*64 + kp*16;                                   \
    load_lds16(Ag + (long)grow*K       + kof, (void*)(&As8[bb][grow*64       + kp*16])); \
    load_lds16(Ag + (long)(64+grow)*K  + kof, (void*)(&As8[bb][(64+grow)*64  + kp*16])); \
    load_lds16(Bg + (long)grow*K       + kof, (void*)(&Bs8[bb][grow*64       + kp*16])); \
    load_lds16(Bg + (long)(64+grow)*K  + kof, (void*)(&Bs8[bb][(64+grow)*64  + kp*16])); \
  } while(0)

  #define MFMA16(afq, bfq)                                                    \
    _Pragma("unroll")                                                         \
    for(int i=0;i<4;i++)                                                      \
      _Pragma("unroll")                                                       \
      for(int j=0;j<4;j++)                                                    \
        acc[i][j] = __builtin_amdgcn_mfma_f32_16x16x32_fp8_fp8(afq[i], bfq[j], acc[i][j], 0, 0, 0)

  STAGE_F8(0, 0);
  STAGE_F8(1, 1);

  for(int tp = 0; tp < nkt/2; tp++){
    // ================= even tile t=2*tp (buffer 0) =================
    asm volatile("s_waitcnt vmcnt(4)" ::: "memory");
    __builtin_amdgcn_s_barrier();
    __builtin_amdgcn_sched_barrier(0);

    long af[2][4], bfr[2][4];
    #pragma unroll
    for(int i=0;i<4;i++) DSRD0(af[0][i],  adrA[0][i]);
    #pragma unroll
    for(int i=0;i<4;i++) DSRD0(af[1][i],  adrA[1][i]);
    #pragma unroll
    for(int j=0;j<4;j++) DSRD0(bfr[0][j], adrB[0][j]);
    #pragma unroll
    for(int j=0;j<4;j++) DSRD0(bfr[1][j], adrB[1][j]);

    asm volatile("s_waitcnt lgkmcnt(0)" ::: "memory");
    __builtin_amdgcn_sched_barrier(0);
    __builtin_amdgcn_s_barrier();                    // all reads done: buffer free
    __builtin_amdgcn_sched_barrier(0);

    if (tp < nkt/2 - 1) STAGE_F8(0, 2*tp + 2);       // async refill, 2 iters flight

    __builtin_amdgcn_s_setprio(1);
    MFMA16(af[0], bfr[0]);
    MFMA16(af[1], bfr[1]);
    __builtin_amdgcn_s_setprio(0);

    // ================= odd tile t=2*tp+1 (buffer 1, offset:8192) ===
    if (tp < nkt/2 - 1) asm volatile("s_waitcnt vmcnt(4)" ::: "memory");
    else                asm volatile("s_waitcnt vmcnt(0)" ::: "memory");
    __builtin_amdgcn_s_barrier();
    __builtin_amdgcn_sched_barrier(0);

    long ag[2][4], bgr[2][4];
    #pragma unroll
    for(int i=0;i<4;i++) DSRD1(ag[0][i],  adrA[0][i]);
    #pragma unroll
    for(int i=0;i<4;i++) DSRD1(ag[1][i],  adrA[1][i]);
    #pragma unroll
    for(int j=0;j<4;j++) DSRD1(bgr[0][j], adrB[0][j]);
    #pragma unroll
    for(int j=0;j<4;j++) DSRD1(bgr[1][j], adrB[1][j]);

    asm volatile("s_waitcnt lgkmcnt(0)" ::: "memory");
    __builtin_amdgcn_sched_barrier(0);
    __builtin_amdgcn_s_barrier();                    // all reads done: buffer free
    __builtin_amdgcn_sched_barrier(0);

    if (tp < nkt/2 - 1) STAGE_F8(1, 2*tp + 3);       // async refill, 2 iters flight

    __builtin_amdgcn_s_setprio(1);
    MFMA16(ag[0], bgr[0]);
    MFMA16(ag[1], bgr[1]);
    __builtin_amdgcn_s_setprio(0);
  }
  #undef STAGE_F8
  #undef MFMA16
  #undef DSRD0
  #undef DSRD1

  // fixed-offset sum-exp partials per 128-col tile (sm2 lives in As8 space;
  // all As8 ds_reads retired at the last in-loop lgkmcnt(0)+barrier)
  #pragma unroll
  for(int i=0;i<4;i++){
    #pragma unroll
    for(int r=0;r<4;r++){
      float sv = 0.f;
      #pragma unroll
      for(int j=0;j<4;j++) sv += __expf(acc[i][j][r]*SCALE - LSE_OFF);
      #pragma unroll
      for(int d=1; d<16; d<<=1) sv += __shfl_xor(sv, d);
      if (rl == 0) sm2[wr][i*16 + rq*4 + r][wc] = sv;
    }
  }
  __syncthreads();
  if (tid < 128){
    int wr2 = tid >> 6, rowl = tid & 63;
    part[(m0 + wr2*64 + rowl)*tiles_n + nt] = sm2[wr2][rowl][0] + sm2[wr2][rowl][1];
  }
}

// ---------------- target logit (bf16 inputs) ----------------
__global__ __launch_bounds__(256) void tlogit_kernel(const unsigned short* __restrict__ outb,
    const unsigned short* __restrict__ embb, const int* __restrict__ tgt,
    float* __restrict__ TL)
{
  long gw = (long)blockIdx.x*4 + (threadIdx.x >> 6);
  int l = threadIdx.x & 63;
  int t = (int)(gw >> 6), b = (int)(gw & 63);
  int tg = tgt[b*S_DIM + t];
  const unsigned short* o = outb + gw*F_DIM;
  const unsigned short* e = embb + (long)tg*F_DIM;
  short8 ov = *(const short8*)(o + l*8);
  short8 ev = *(const short8*)(e + l*8);
  float s = 0.f;
  #pragma unroll
  for(int i=0;i<8;i++) s += bf2f((unsigned short)ov[i]) * bf2f((unsigned short)ev[i]);
  s = wsum(s);
  if (l == 0) TL[gw] = s * SCALE;
}

// ---------------- sum partials -> nll ----------------
__global__ __launch_bounds__(256) void lse_kernel(const float* __restrict__ part,
    const float* __restrict__ TL, float* __restrict__ nll)
{
  long row = (long)blockIdx.x*4 + (threadIdx.x >> 6);
  int l = threadIdx.x & 63;
  float S = 0.f;
  for(int c = l; c < NT_LOG; c += 64)
    S += part[row*NT_LOG + c];
  S = wsum(S);
  if (l == 0) nll[row] = (LSE_OFF + logf(S)) - TL[row];
}

// ---------------- final loss ----------------
__global__ __launch_bounds__(256) void loss_kernel(const float* __restrict__ nll,
    const int* __restrict__ tgt, float* __restrict__ out)
{
  int t = threadIdx.x;
  float s = 0.f; int cnt = 0;
  for(int b = 0; b < B_DIM; b++){
    int v = tgt[b*S_DIM + t];
    if (v != 0){ s += nll[(long)t*B_DIM + b]; cnt++; }
  }
  float li = s / fmaxf((float)cnt, 1.f);
  li = wsum(li);
  __shared__ float red[4];
  if ((t & 63) == 0) red[t >> 6] = li;
  __syncthreads();
  if (t == 0) out[0] = (red[0]+red[1]+red[2]+red[3]) * (1.f/256.f);
}

extern "C" void kernel_launch(void* const* d_in, const int* in_sizes, int n_in,
                              void* d_out, int out_size, void* d_ws, size_t ws_size,
                              hipStream_t stream)
{
  const int*   inp   = (const int*)d_in[0];
  const int*   tgt   = (const int*)d_in[1];
  const float* see   = (const float*)d_in[2];
  const float* bias  = (const float*)d_in[3];
  const float* W_in  = (const float*)d_in[4];
  const float* b_in  = (const float*)d_in[5];
  const float* W_out = (const float*)d_in[6];
  const float* b_out = (const float*)d_in[7];
  const float* ln_g  = (const float*)d_in[8];
  const float* ln_b  = (const float*)d_in[9];
  const float* emb   = (const float*)d_in[10];

  // Workspace plan — peak ~205 MB. Aliases safe by stream order:
  //   XLN  aliases ZV     (ZV dead after recurrence; XLN born at ln)
  //   OUT8 aliases VECSb  (VECSb dead after Z-gemm; OUT8 born at FFN2)
  //   PART aliases Hb     (Hb dead after FFN2; PART born at logits gemm)
  char* p = (char*)d_ws;
  unsigned short* CONTB= (unsigned short*)p; p += (size_t)ROWS*F_DIM*2;   // 16.8 MB
  unsigned short* Hb   = (unsigned short*)p; p += (size_t)ROWS*H_DIM*2;   // 67.1 MB
  unsigned short* OUTb = (unsigned short*)p; p += (size_t)ROWS*F_DIM*2;   // 16.8 MB
  unsigned short* EMBb = (unsigned short*)p; p += (size_t)V_DIM*F_DIM*2;  // 32.8 MB
  unsigned char* EMB8  = (unsigned char*)p;  p += (size_t)V_DIM*F_DIM;    // 16.4 MB
  unsigned short* WINb = (unsigned short*)p; p += (size_t)H_DIM*F_DIM*2;  //  2.1 MB
  unsigned short* WOUTb= (unsigned short*)p; p += (size_t)F_DIM*H_DIM*2;  //  2.1 MB
  float* TL            = (float*)p;          p += (size_t)ROWS*4;
  float* NLL           = (float*)p;          p += (size_t)ROWS*4;
  unsigned short* VECSb= (unsigned short*)p; p += (size_t)ROWS*F_DIM*2;   // 16.8 MB
  unsigned int* ZV     = (unsigned int*)p;   p += (size_t)ROWS*F_DIM*4;   // 33.6 MB
  unsigned short* SEETT= (unsigned short*)p; p += (size_t)F_DIM*F_DIM*2;  //  0.5 MB
  unsigned char* SEEB8 = (unsigned char*)p;  p += (size_t)F_DIM*F_DIM;    //  0.26 MB
  // aliases
  unsigned short* XLN  = (unsigned short*)ZV;      // 16.8 of 33.6 MB
  unsigned char* OUT8  = (unsigned char*)VECSb;    //  8.4 of 16.8 MB
  float* PART          = (float*)Hb;               // 16.4 of 67.1 MB

  // independent prep
  cast_emb<<<4096, 256, 0, stream>>>(emb, EMBb, EMB8);
  cast_w<<<2048, 256, 0, stream>>>(W_in,  WINb,  H_DIM*F_DIM);
  cast_w<<<2048, 256, 0, stream>>>(W_out, WOUTb, F_DIM*H_DIM);
  prep_see<<<512, 256, 0, stream>>>(see, SEETT, SEEB8);
  gather_vecs<<<ROWS/4, 256, 0, stream>>>(emb, inp, VECSb);

  // ZV = pack(vecs, vecs @ see_top + bias)  — direct packed epilogue (MODE 5)
  gemm_bt<5><<<128*4, 256, 0, stream>>>(VECSb, SEETT, bias, nullptr, nullptr,
                                        VECSb, ZV, ROWS, F_DIM, F_DIM, 128, 4);

  // batch-parallel recurrence: 4 WGs, fp8-resident weights, no inter-block sync
  recurrence_batch<<<4, 512, 0, stream>>>(ZV, SEEB8, CONTB);

  // downstream
  ln_kernel<<<ROWS/4, 256, 0, stream>>>(CONTB, ln_g, ln_b, XLN);
  gemm_bt<0><<<128*16, 256, 0, stream>>>(XLN,  WINb,  b_in,  Hb,   nullptr,
                                         nullptr, nullptr, ROWS, H_DIM, F_DIM, 128, 16);
  gemm_bt<4><<<128*4,  256, 0, stream>>>(Hb,   WOUTb, b_out, OUTb, OUT8,
                                         nullptr, nullptr, ROWS, F_DIM, H_DIM, 128, 4);
  tlogit_kernel<<<ROWS/4, 256, 0, stream>>>(OUTb, EMBb, tgt, TL);
  gemm_f8_logits<<<128*NT_LOG, 256, 0, stream>>>(OUT8, EMB8, PART, ROWS, V_DIM, F_DIM, 128, NT_LOG);
  lse_kernel<<<ROWS/4, 256, 0, stream>>>(PART, TL, NLL);
  loss_kernel<<<1, 256, 0, stream>>>(NLL, tgt, (float*)d_out);
}